// Round 7
// baseline (139.495 us; speedup 1.0000x reference)
//
#include <hip/hip_runtime.h>

// B=4, S=4096, D=64, fp32. Softmax over QUERY axis (per key-column norm):
//   out[b,q,:] = sum_k exp(s[q,k]) * (1/sum_q' exp(s[q',k])) * V[k,:],  s = Q.K^T/8
// v8: L2-TRAFFIC REDUCTION. v6 measured 87.8us ~= L2-BW floor (2.1GB @ ~23TB/s).
// Double K/V reuse: each wave computes 32 q (2 qg frags) instead of 16; block =
// 8 waves = 8 k-eighths sharing one 32-q tile; grid 512 (16 waves/CU as v6).
// Traffic halves to ~1.05GB. Images stay fragment-ordered (64-lane contiguous
// 1KB per load). Inner loop: zero LDS, permuted-VT in-register P (v5 trick).
// Merge: 8 k-partials, two 16-q phases (LDS 34.8KB). Numerics identical.

#define B_N 4
#define S_N 4096
#define D_N 64
#define BS_N (B_N * S_N)
#define NCHUNK 128            // 32-row chunks per batch
#define IMG_CH 8192           // bytes per chunk in every image
#define QSC (0.125f * 1.44269504088896f)

typedef __attribute__((ext_vector_type(4))) float f32x4;
typedef __attribute__((ext_vector_type(2))) float f32x2;
typedef __attribute__((ext_vector_type(8))) short short8;
typedef __attribute__((ext_vector_type(4))) unsigned u32x4;
typedef unsigned long long u64;
typedef unsigned char uchar;

#define MFMA16(A, Bf, C) __builtin_amdgcn_mfma_f32_16x16x32_bf16((A), (Bf), (C), 0, 0, 0)

// Truncation hi/lo split: x == hi + lo + O(2^-16 x); residual exact in fp32.
__device__ __forceinline__ void split1(float x, unsigned short& h, unsigned short& l) {
  union { float f; unsigned u; } t; t.f = x;
  h = (unsigned short)(t.u >> 16);
  union { unsigned u; float f; } hv; hv.u = ((unsigned)h) << 16;
  union { float f; unsigned u; } r; r.f = x - hv.f;
  l = (unsigned short)(r.u >> 16);
}

__device__ __forceinline__ void splitFrag8(const f32x4 a, const f32x4 b, short8& hi, short8& lo) {
#pragma unroll
  for (int j = 0; j < 4; ++j) { unsigned short h, l; split1(a[j], h, l); hi[j] = (short)h; lo[j] = (short)l; }
#pragma unroll
  for (int j = 0; j < 4; ++j) { unsigned short h, l; split1(b[j], h, l); hi[4 + j] = (short)h; lo[4 + j] = (short)l; }
}

// ---------------------------------------------------------------------------
// prepKQ: fp32 [B*S][64] -> FRAGMENT-ORDERED chunk images.
// Chunk (8KB) = 2 half-chunks (kt) x 4 segs (hi-d0..31, hi-d32..63, lo-d0..31,
// lo-d32..63) x 1KB; byte addr = kt*4096 + p*1024 + lane*16, lane = g4*16+l15.
// grid 1024: blocks 0..511 = K (scale 1), 512..1023 = Q (scale QSC).
// ---------------------------------------------------------------------------
__global__ __launch_bounds__(256) void sdpa_prepKQ(const float* __restrict__ K,
                                                   const float* __restrict__ Qm,
                                                   uchar* __restrict__ Kimg,
                                                   uchar* __restrict__ Qimg) {
  const int sel = blockIdx.x >> 9;
  const int c = blockIdx.x & 127;
  const int b = (blockIdx.x >> 7) & 3;
  const float* src = sel ? Qm : K;
  uchar* img = sel ? Qimg : Kimg;
  const float scale = sel ? QSC : 1.0f;
  const int t = threadIdx.x;
  const int r = t >> 3;          // 0..31 row in chunk
  const int d0 = (t & 7) * 8;    // 0..56
  const float* s = src + ((size_t)(b * S_N + c * 32 + r)) * D_N + d0;
  f32x4 x0 = *(const f32x4*)(s);
  f32x4 x1 = *(const f32x4*)(s + 4);
  x0 *= scale; x1 *= scale;
  short8 h8, l8;
  splitFrag8(x0, x1, h8, l8);
  const int kt = r >> 4;
  const int lane = ((d0 & 31) >> 3) * 16 + (r & 15);
  const int ph = d0 >> 5;  // 0/1
  uchar* base = img + ((size_t)(b * NCHUNK + c)) * IMG_CH + kt * 4096 + lane * 16;
  *(short8*)(base + ph * 1024) = h8;
  *(short8*)(base + (2 + ph) * 1024) = l8;
}

// ---------------------------------------------------------------------------
// stats6: lPart[qs][b][k] = sum over q-slice qs (512 q) of exp2(min(s,86)).
// grid 1024 (16 waves/CU), block 256; wave w -> q-slice. 32 k resident.
// ---------------------------------------------------------------------------
__global__ __launch_bounds__(256, 4) void sdpa_stats6(const uchar* __restrict__ Kimg,
                                                      const uchar* __restrict__ Qimg,
                                                      float* __restrict__ lPart) {
  const int tid = threadIdx.x, lane = tid & 63, w = tid >> 6;
  const int l15 = lane & 15, g4 = lane >> 4;
  const int xcd = blockIdx.x & 7;
  const int b = xcd >> 1;
  const int r = blockIdx.x >> 3;                  // [0,128)
  const int kt = ((r & 63) << 1) | (xcd & 1);     // [0,128) 32-k tile
  const int qs = ((r >> 6) << 2) | w;             // [0,8) q-slice of 512

  const uchar* kc = Kimg + ((size_t)(b * NCHUNK + kt)) * IMG_CH + lane * 16;
  short8 kh[2][2], kl[2][2];
#pragma unroll
  for (int kg = 0; kg < 2; ++kg) {
    kh[kg][0] = *(const short8*)(kc + (kg * 4 + 0) * 1024);
    kh[kg][1] = *(const short8*)(kc + (kg * 4 + 1) * 1024);
    kl[kg][0] = *(const short8*)(kc + (kg * 4 + 2) * 1024);
    kl[kg][1] = *(const short8*)(kc + (kg * 4 + 3) * 1024);
  }

  float lacc[2][4];
#pragma unroll
  for (int kg = 0; kg < 2; ++kg)
#pragma unroll
    for (int rr = 0; rr < 4; ++rr) lacc[kg][rr] = 0.f;

  const uchar* Qbase = Qimg + ((size_t)(b * NCHUNK + qs * 16)) * IMG_CH + lane * 16;

  short8 qb[2][2][4];
#pragma unroll
  for (int qt = 0; qt < 2; ++qt)
#pragma unroll
    for (int p = 0; p < 4; ++p)
      qb[0][qt][p] = *(const short8*)(Qbase + (qt * 4 + p) * 1024);

#pragma unroll 2
  for (int it = 0; it < 16; ++it) {
    const int cur = it & 1, nxt = cur ^ 1;
    if (it < 15) {
      const uchar* Qn = Qbase + (size_t)(it + 1) * IMG_CH;
#pragma unroll
      for (int qt = 0; qt < 2; ++qt)
#pragma unroll
        for (int p = 0; p < 4; ++p)
          qb[nxt][qt][p] = *(const short8*)(Qn + (qt * 4 + p) * 1024);
    }
#pragma unroll
    for (int qt = 0; qt < 2; ++qt) {
      short8 bh0 = qb[cur][qt][0], bh1 = qb[cur][qt][1];
      short8 bl0 = qb[cur][qt][2], bl1 = qb[cur][qt][3];
#pragma unroll
      for (int kg = 0; kg < 2; ++kg) {
        f32x4 acc = {0.f, 0.f, 0.f, 0.f};
        acc = MFMA16(kl[kg][0], bh0, acc);
        acc = MFMA16(kh[kg][0], bl0, acc);
        acc = MFMA16(kh[kg][0], bh0, acc);
        acc = MFMA16(kl[kg][1], bh1, acc);
        acc = MFMA16(kh[kg][1], bl1, acc);
        acc = MFMA16(kh[kg][1], bh1, acc);
#pragma unroll
        for (int rr = 0; rr < 4; ++rr)
          lacc[kg][rr] += exp2f(fminf(acc[rr], 86.f));
      }
    }
  }

#pragma unroll
  for (int off = 1; off < 16; off <<= 1)
#pragma unroll
    for (int kg = 0; kg < 2; ++kg)
#pragma unroll
      for (int rr = 0; rr < 4; ++rr)
        lacc[kg][rr] += __shfl_xor(lacc[kg][rr], off);

  if (l15 == 0) {
#pragma unroll
    for (int kg = 0; kg < 2; ++kg)
#pragma unroll
      for (int rr = 0; rr < 4; ++rr)
        lPart[(size_t)qs * BS_N + b * S_N + kt * 32 + kg * 16 + (g4 << 2) + rr] = lacc[kg][rr];
  }
}

__global__ void sdpa_finalize8(const float* __restrict__ lPart, float* __restrict__ rcpl) {
  int i = blockIdx.x * 256 + threadIdx.x;
  if (i < BS_N) {
    float s = 0.f;
#pragma unroll
    for (int j = 0; j < 8; ++j) s += lPart[(size_t)j * BS_N + i];
    rcpl[i] = 1.0f / s;
  }
}

// ---------------------------------------------------------------------------
// prepV6: fragment-ordered VT chunk images with PERMUTED k-columns.
// Chunk = 4 dt x [hi 1KB | lo 1KB]; addr = dt*2048 + half*1024 + lane*16;
// d = dt*16 + (lane&15), col slots cc = (lane>>4)*8..+7,
// value = split(V[k=perm(cc)][d]*rcpl[k]), perm(c)=((c>>2)&1)*16+((c>>3)<<2)+(c&3).
// ---------------------------------------------------------------------------
__global__ __launch_bounds__(256) void sdpa_prepV6(const float* __restrict__ V,
                                                   const float* __restrict__ rcpl,
                                                   uchar* __restrict__ VT) {
  __shared__ float Vs[32][65];
  __shared__ float rls[32];
  const int c = blockIdx.x & 127;
  const int b = blockIdx.x >> 7;
  const int t = threadIdx.x;
  {
    const int k = t >> 3;
    const int d0 = (t & 7) * 8;
    const float* src = V + ((size_t)(b * S_N + c * 32 + k)) * D_N + d0;
    f32x4 x0 = *(const f32x4*)(src);
    f32x4 x1 = *(const f32x4*)(src + 4);
#pragma unroll
    for (int j = 0; j < 4; ++j) { Vs[k][d0 + j] = x0[j]; Vs[k][d0 + 4 + j] = x1[j]; }
    if (t < 32) rls[t] = rcpl[b * S_N + c * 32 + t];
  }
  __syncthreads();
  const int d = t >> 2;
  const int kg = t & 3;
  short8 h8, l8;
#pragma unroll
  for (int j = 0; j < 8; ++j) {
    const int cc = kg * 8 + j;
    const int k = (((cc >> 2) & 1) << 4) + (((cc >> 3)) << 2) + (cc & 3);
    float v = Vs[k][d] * rls[k];
    unsigned short h, l; split1(v, h, l);
    h8[j] = (short)h; l8[j] = (short)l;
  }
  const int lane = kg * 16 + (d & 15);
  uchar* base = VT + ((size_t)(b * NCHUNK + c)) * IMG_CH + (d >> 4) * 2048 + lane * 16;
  *(short8*)(base) = h8;
  *(short8*)(base + 1024) = l8;
}

// ---------------------------------------------------------------------------
// apply8: grid 512 = b(4, XCD-paired) x qt(128 tiles of 32 q); block 512 =
// 8 waves, wave w = k-EIGHTH (16 chunks = 512 k); all waves share the 32-q
// tile (2 qg frags each -> 2x K/V reuse vs v6). 2 blocks/CU = 16 waves/CU.
// Inner loop: NO LDS, 64-lane-contiguous loads, in-register P (permuted VT).
// Merge 8 k-partials in two 16-q LDS phases.
// ---------------------------------------------------------------------------
__global__ __launch_bounds__(512, 4) void sdpa_apply8(const float* __restrict__ Q,
                                                      const uchar* __restrict__ Kimg,
                                                      const uchar* __restrict__ VTimg,
                                                      float* __restrict__ Out) {
  __shared__ __attribute__((aligned(16))) float Comb[8][16 * 68];  // 34816 B

  const int tid = threadIdx.x, lane = tid & 63, w = tid >> 6;
  const int l15 = lane & 15, g4 = lane >> 4;
  const int xcd = blockIdx.x & 7;
  const int b = xcd >> 1;
  const int qt = ((blockIdx.x >> 3) << 1) | (xcd & 1);  // [0,128)

  // Q B-frags: the block's 32 q rows (2 x 16), scaled + hi/lo split
  short8 qh[2][2], ql[2][2];
#pragma unroll
  for (int qg = 0; qg < 2; ++qg) {
    const int qRow = qt * 32 + qg * 16 + l15;
    const float* Qp = Q + ((size_t)(b * S_N + qRow)) * D_N;
    f32x4 x0 = *(const f32x4*)(Qp + g4 * 8);
    f32x4 x1 = *(const f32x4*)(Qp + g4 * 8 + 4);
    f32x4 y0 = *(const f32x4*)(Qp + 32 + g4 * 8);
    f32x4 y1 = *(const f32x4*)(Qp + 36 + g4 * 8);
    x0 *= QSC; x1 *= QSC; y0 *= QSC; y1 *= QSC;
    splitFrag8(x0, x1, qh[qg][0], ql[qg][0]);
    splitFrag8(y0, y1, qh[qg][1], ql[qg][1]);
  }

  f32x4 accO[2][4];
#pragma unroll
  for (int qg = 0; qg < 2; ++qg)
#pragma unroll
    for (int dt = 0; dt < 4; ++dt) accO[qg][dt] = (f32x4){0.f, 0.f, 0.f, 0.f};

  const uchar* Kc = Kimg + ((size_t)(b * NCHUNK + w * 16)) * IMG_CH + lane * 16;
  const uchar* Vc = VTimg + ((size_t)(b * NCHUNK + w * 16)) * IMG_CH + lane * 16;

  // prologue: K chunk 0 resident
  short8 kb[2][2][4];  // [buf][kt][ah0,ah1,al0,al1]
#pragma unroll
  for (int kt = 0; kt < 2; ++kt)
#pragma unroll
    for (int p = 0; p < 4; ++p)
      kb[0][kt][p] = *(const short8*)(Kc + (kt * 4 + p) * 1024);

#pragma unroll 2
  for (int it = 0; it < 16; ++it) {
    const int cur = it & 1;
    const int nxt = cur ^ 1;

    // V(it): issued at top, consumed after QK+exp
    short8 vv[4][2];
    {
      const uchar* Vn = Vc + (size_t)it * IMG_CH;
#pragma unroll
      for (int dt = 0; dt < 4; ++dt) {
        vv[dt][0] = *(const short8*)(Vn + dt * 2048);
        vv[dt][1] = *(const short8*)(Vn + dt * 2048 + 1024);
      }
    }

    // prefetch K(it+1)
    if (it < 15) {
      const uchar* Kn = Kc + (size_t)(it + 1) * IMG_CH;
#pragma unroll
      for (int kt = 0; kt < 2; ++kt)
#pragma unroll
        for (int p = 0; p < 4; ++p)
          kb[nxt][kt][p] = *(const short8*)(Kn + (kt * 4 + p) * 1024);
    }

    // QK(it), swapped (A=K, B=Q): D[k][q]; lane holds k = kt*16+g4*4+r, q=l15.
    // exp results pack directly into the PV A-fragment (permuted-VT trick).
    u32x4 paH[2], paL[2];
#pragma unroll
    for (int kt = 0; kt < 2; ++kt) {
      short8 ah0 = kb[cur][kt][0], ah1 = kb[cur][kt][1];
      short8 al0 = kb[cur][kt][2], al1 = kb[cur][kt][3];
#pragma unroll
      for (int qg = 0; qg < 2; ++qg) {
        f32x4 acc = {0.f, 0.f, 0.f, 0.f};
        acc = MFMA16(al0, qh[qg][0], acc);
        acc = MFMA16(ah0, ql[qg][0], acc);
        acc = MFMA16(ah0, qh[qg][0], acc);
        acc = MFMA16(al1, qh[qg][1], acc);
        acc = MFMA16(ah1, ql[qg][1], acc);
        acc = MFMA16(ah1, qh[qg][1], acc);
#pragma unroll
        for (int pair = 0; pair < 2; ++pair) {
          float p0 = exp2f(fminf(acc[2 * pair + 0], 86.f));
          float p1 = exp2f(fminf(acc[2 * pair + 1], 86.f));
          unsigned short h0, l0, h1, l1;
          split1(p0, h0, l0);
          split1(p1, h1, l1);
          paH[qg][kt * 2 + pair] = (unsigned)h0 | ((unsigned)h1 << 16);
          paL[qg][kt * 2 + pair] = (unsigned)l0 | ((unsigned)l1 << 16);
        }
      }
    }

    // PV(it): A = in-register P frags, B = permuted-VT frags
    short8 pah[2], pal[2];
#pragma unroll
    for (int qg = 0; qg < 2; ++qg) {
      pah[qg] = __builtin_bit_cast(short8, paH[qg]);
      pal[qg] = __builtin_bit_cast(short8, paL[qg]);
    }
#pragma unroll
    for (int dt = 0; dt < 4; ++dt)
#pragma unroll
      for (int qg = 0; qg < 2; ++qg) {
        accO[qg][dt] = MFMA16(pal[qg], vv[dt][0], accO[qg][dt]);
        accO[qg][dt] = MFMA16(pah[qg], vv[dt][1], accO[qg][dt]);
        accO[qg][dt] = MFMA16(pah[qg], vv[dt][0], accO[qg][dt]);
      }
  }

  // merge 8 k-eighth partials, two 16-q phases (LDS = 34.8KB)
#pragma unroll
  for (int qg = 0; qg < 2; ++qg) {
    {
      float* CombW = Comb[w];
#pragma unroll
      for (int dt = 0; dt < 4; ++dt)
#pragma unroll
        for (int r = 0; r < 4; ++r)
          CombW[((g4 << 2) + r) * 68 + dt * 16 + l15] = accO[qg][dt][r];
    }
    __syncthreads();
    {
      const int row = tid >> 5;        // 0..15
      const int c2 = (tid & 31) * 2;   // 0..62
      f32x2 s = {0.f, 0.f};
#pragma unroll
      for (int w2 = 0; w2 < 8; ++w2)
        s += *(const f32x2*)(&Comb[w2][row * 68 + c2]);
      *(f32x2*)(Out + ((size_t)(b * S_N + qt * 32 + qg * 16 + row)) * D_N + c2) = s;
    }
    __syncthreads();
  }
}

extern "C" void kernel_launch(void* const* d_in, const int* in_sizes, int n_in,
                              void* d_out, int out_size, void* d_ws, size_t ws_size,
                              hipStream_t stream) {
  (void)in_sizes; (void)n_in; (void)out_size;
  const float* Q = (const float*)d_in[0];
  const float* K = (const float*)d_in[1];
  const float* V = (const float*)d_in[2];
  float* out = (float*)d_out;
  uchar* ws = (uchar*)d_ws;

  const size_t imgSz = (size_t)B_N * NCHUNK * IMG_CH;          // 4 MB
  const size_t offK = 0;
  const size_t offQV = imgSz;                                  // Q image; VT aliases after stats
  const size_t offLP = 2 * imgSz;
  const size_t offRC = offLP + (size_t)8 * BS_N * 4;
  const size_t need = offRC + (size_t)BS_N * 4;                // ~8.56 MiB (proven available)

  if (ws_size < need) return;
  float* lPart = (float*)(ws + offLP);
  float* rcpl = (float*)(ws + offRC);

  sdpa_prepKQ<<<dim3(1024), dim3(256), 0, stream>>>(K, Q, ws + offK, ws + offQV);
  sdpa_stats6<<<dim3(1024), dim3(256), 0, stream>>>(ws + offK, ws + offQV, lPart);
  sdpa_finalize8<<<dim3(BS_N / 256), dim3(256), 0, stream>>>(lPart, rcpl);
  sdpa_prepV6<<<dim3(512), dim3(256), 0, stream>>>(V, rcpl, ws + offQV);
  sdpa_apply8<<<dim3(512), dim3(512), 0, stream>>>(Q, ws + offK, ws + offQV, out);
}

// Round 8
// 107.510 us; speedup vs baseline: 1.2975x; 1.2975x over previous
//
#include <hip/hip_runtime.h>

// B=4, S=4096, D=64, fp32. Softmax over QUERY axis (per key-column norm):
//   out[b,q,:] = sum_k exp(s[q,k]) * (1/sum_q' exp(s[q',k])) * V[k,:],  s = Q.K^T/8
// v9: v8's 2x K/V reuse (32 q per wave) REBUILT TO FIT 128 VGPRs (v8 spilled:
// WRITE_SIZE 207MB scratch, 110us). K single-buffered loop-local, V loaded
// per-dt, unroll 1. 8 k-eighth waves share one 32-q tile; grid 512, 16 waves/CU.
// stats8: 64 k resident/wave, 8 Q-chunk stream (16 slices, finalize16).
// Images fragment-ordered (64-lane contiguous 1KB loads). In-register P via
// permuted VT (v5). Numerics identical (hi/lo split, 3-MFMA products).

#define B_N 4
#define S_N 4096
#define D_N 64
#define BS_N (B_N * S_N)
#define NCHUNK 128            // 32-row chunks per batch
#define IMG_CH 8192           // bytes per chunk in every image
#define QSC (0.125f * 1.44269504088896f)

typedef __attribute__((ext_vector_type(4))) float f32x4;
typedef __attribute__((ext_vector_type(2))) float f32x2;
typedef __attribute__((ext_vector_type(8))) short short8;
typedef __attribute__((ext_vector_type(4))) unsigned u32x4;
typedef unsigned char uchar;

#define MFMA16(A, Bf, C) __builtin_amdgcn_mfma_f32_16x16x32_bf16((A), (Bf), (C), 0, 0, 0)

// Truncation hi/lo split: x == hi + lo + O(2^-16 x); residual exact in fp32.
__device__ __forceinline__ void split1(float x, unsigned short& h, unsigned short& l) {
  union { float f; unsigned u; } t; t.f = x;
  h = (unsigned short)(t.u >> 16);
  union { unsigned u; float f; } hv; hv.u = ((unsigned)h) << 16;
  union { float f; unsigned u; } r; r.f = x - hv.f;
  l = (unsigned short)(r.u >> 16);
}

__device__ __forceinline__ void splitFrag8(const f32x4 a, const f32x4 b, short8& hi, short8& lo) {
#pragma unroll
  for (int j = 0; j < 4; ++j) { unsigned short h, l; split1(a[j], h, l); hi[j] = (short)h; lo[j] = (short)l; }
#pragma unroll
  for (int j = 0; j < 4; ++j) { unsigned short h, l; split1(b[j], h, l); hi[4 + j] = (short)h; lo[4 + j] = (short)l; }
}

// ---------------------------------------------------------------------------
// prepKQ: fp32 [B*S][64] -> FRAGMENT-ORDERED chunk images.
// Chunk (8KB) = 2 half-chunks (kt16) x 4 segs (hi-d0..31, hi-d32..63,
// lo-d0..31, lo-d32..63) x 1KB; addr = kt16*4096 + p*1024 + lane*16.
// grid 1024: blocks 0..511 = K (scale 1), 512..1023 = Q (scale QSC).
// ---------------------------------------------------------------------------
__global__ __launch_bounds__(256) void sdpa_prepKQ(const float* __restrict__ K,
                                                   const float* __restrict__ Qm,
                                                   uchar* __restrict__ Kimg,
                                                   uchar* __restrict__ Qimg) {
  const int sel = blockIdx.x >> 9;
  const int c = blockIdx.x & 127;
  const int b = (blockIdx.x >> 7) & 3;
  const float* src = sel ? Qm : K;
  uchar* img = sel ? Qimg : Kimg;
  const float scale = sel ? QSC : 1.0f;
  const int t = threadIdx.x;
  const int r = t >> 3;          // 0..31 row in chunk
  const int d0 = (t & 7) * 8;    // 0..56
  const float* s = src + ((size_t)(b * S_N + c * 32 + r)) * D_N + d0;
  f32x4 x0 = *(const f32x4*)(s);
  f32x4 x1 = *(const f32x4*)(s + 4);
  x0 *= scale; x1 *= scale;
  short8 h8, l8;
  splitFrag8(x0, x1, h8, l8);
  const int kt = r >> 4;
  const int lane = ((d0 & 31) >> 3) * 16 + (r & 15);
  const int ph = d0 >> 5;  // 0/1
  uchar* base = img + ((size_t)(b * NCHUNK + c)) * IMG_CH + kt * 4096 + lane * 16;
  *(short8*)(base + ph * 1024) = h8;
  *(short8*)(base + (2 + ph) * 1024) = l8;
}

// ---------------------------------------------------------------------------
// stats8: lPart[qs][b][k] = sum over q-slice qs (16 slices x 256 q) of
// exp2(min(s,86)). grid 1024 (16 waves/CU), block 256; wave w -> qs = qsg*4+w.
// 64 k register-resident per wave (kh/kl[4][2]); streams 8 Q chunks.
// ---------------------------------------------------------------------------
__global__ __launch_bounds__(256, 4) void sdpa_stats8(const uchar* __restrict__ Kimg,
                                                      const uchar* __restrict__ Qimg,
                                                      float* __restrict__ lPart) {
  const int tid = threadIdx.x, lane = tid & 63, w = tid >> 6;
  const int l15 = lane & 15, g4 = lane >> 4;
  const int xcd = blockIdx.x & 7;
  const int b = xcd >> 1;
  const int r = blockIdx.x >> 3;                  // [0,128)
  const int kt = ((r & 31) << 1) | (xcd & 1);     // [0,64) 64-k tile
  const int qs = ((r >> 5) << 2) | w;             // [0,16) 256-q slice

  // K resident: kg 0..3 -> rows kt*64 + kg*16 + l15; chunk kt*2+(kg>>1), half kg&1
  short8 kh[4][2], kl[4][2];
#pragma unroll
  for (int kg = 0; kg < 4; ++kg) {
    const uchar* kc = Kimg + ((size_t)(b * NCHUNK + kt * 2 + (kg >> 1))) * IMG_CH
                    + (kg & 1) * 4096 + lane * 16;
    kh[kg][0] = *(const short8*)(kc);
    kh[kg][1] = *(const short8*)(kc + 1024);
    kl[kg][0] = *(const short8*)(kc + 2048);
    kl[kg][1] = *(const short8*)(kc + 3072);
  }

  float lacc[4][4];
#pragma unroll
  for (int kg = 0; kg < 4; ++kg)
#pragma unroll
    for (int rr = 0; rr < 4; ++rr) lacc[kg][rr] = 0.f;

  const uchar* Qbase = Qimg + ((size_t)(b * NCHUNK + qs * 8)) * IMG_CH + lane * 16;

#pragma unroll 1
  for (int it = 0; it < 8; ++it) {
    const uchar* Qc = Qbase + (size_t)it * IMG_CH;
#pragma unroll
    for (int qt = 0; qt < 2; ++qt) {
      short8 bh0 = *(const short8*)(Qc + qt * 4096);
      short8 bh1 = *(const short8*)(Qc + qt * 4096 + 1024);
      short8 bl0 = *(const short8*)(Qc + qt * 4096 + 2048);
      short8 bl1 = *(const short8*)(Qc + qt * 4096 + 3072);
#pragma unroll
      for (int kg = 0; kg < 4; ++kg) {
        f32x4 acc = {0.f, 0.f, 0.f, 0.f};
        acc = MFMA16(kl[kg][0], bh0, acc);
        acc = MFMA16(kh[kg][0], bl0, acc);
        acc = MFMA16(kh[kg][0], bh0, acc);
        acc = MFMA16(kl[kg][1], bh1, acc);
        acc = MFMA16(kh[kg][1], bl1, acc);
        acc = MFMA16(kh[kg][1], bh1, acc);
#pragma unroll
        for (int rr = 0; rr < 4; ++rr)
          lacc[kg][rr] += exp2f(fminf(acc[rr], 86.f));
      }
    }
  }

#pragma unroll
  for (int off = 1; off < 16; off <<= 1)
#pragma unroll
    for (int kg = 0; kg < 4; ++kg)
#pragma unroll
      for (int rr = 0; rr < 4; ++rr)
        lacc[kg][rr] += __shfl_xor(lacc[kg][rr], off);

  if (l15 == 0) {
#pragma unroll
    for (int kg = 0; kg < 4; ++kg)
#pragma unroll
      for (int rr = 0; rr < 4; ++rr)
        lPart[(size_t)qs * BS_N + b * S_N + kt * 64 + kg * 16 + (g4 << 2) + rr] = lacc[kg][rr];
  }
}

__global__ void sdpa_finalize16(const float* __restrict__ lPart, float* __restrict__ rcpl) {
  int i = blockIdx.x * 256 + threadIdx.x;
  if (i < BS_N) {
    float s = 0.f;
#pragma unroll
    for (int j = 0; j < 16; ++j) s += lPart[(size_t)j * BS_N + i];
    rcpl[i] = 1.0f / s;
  }
}

// ---------------------------------------------------------------------------
// prepV6: fragment-ordered VT chunk images with PERMUTED k-columns.
// Chunk = 4 dt x [hi 1KB | lo 1KB]; addr = dt*2048 + half*1024 + lane*16;
// d = dt*16 + (lane&15), col slots cc = (lane>>4)*8..+7,
// value = split(V[k=perm(cc)][d]*rcpl[k]), perm(c)=((c>>2)&1)*16+((c>>3)<<2)+(c&3).
// ---------------------------------------------------------------------------
__global__ __launch_bounds__(256) void sdpa_prepV6(const float* __restrict__ V,
                                                   const float* __restrict__ rcpl,
                                                   uchar* __restrict__ VT) {
  __shared__ float Vs[32][65];
  __shared__ float rls[32];
  const int c = blockIdx.x & 127;
  const int b = blockIdx.x >> 7;
  const int t = threadIdx.x;
  {
    const int k = t >> 3;
    const int d0 = (t & 7) * 8;
    const float* src = V + ((size_t)(b * S_N + c * 32 + k)) * D_N + d0;
    f32x4 x0 = *(const f32x4*)(src);
    f32x4 x1 = *(const f32x4*)(src + 4);
#pragma unroll
    for (int j = 0; j < 4; ++j) { Vs[k][d0 + j] = x0[j]; Vs[k][d0 + 4 + j] = x1[j]; }
    if (t < 32) rls[t] = rcpl[b * S_N + c * 32 + t];
  }
  __syncthreads();
  const int d = t >> 2;
  const int kg = t & 3;
  short8 h8, l8;
#pragma unroll
  for (int j = 0; j < 8; ++j) {
    const int cc = kg * 8 + j;
    const int k = (((cc >> 2) & 1) << 4) + (((cc >> 3)) << 2) + (cc & 3);
    float v = Vs[k][d] * rls[k];
    unsigned short h, l; split1(v, h, l);
    h8[j] = (short)h; l8[j] = (short)l;
  }
  const int lane = kg * 16 + (d & 15);
  uchar* base = VT + ((size_t)(b * NCHUNK + c)) * IMG_CH + (d >> 4) * 2048 + lane * 16;
  *(short8*)(base) = h8;
  *(short8*)(base + 1024) = l8;
}

// ---------------------------------------------------------------------------
// apply9: grid 512 = b(4, XCD-paired) x qt(128 tiles of 32 q); block 512 =
// 8 waves, wave w = k-EIGHTH (16 chunks); all waves share the 32-q tile
// (2 qg frags -> 2x K/V reuse). 16 waves/CU. Register-lean: K loop-local
// single-buffer, V per-dt, unroll 1 (fits 128 VGPR; v8 spilled at ~190).
// Inner loop: NO LDS, 64-lane-contiguous loads, in-register P (permuted VT).
// ---------------------------------------------------------------------------
__global__ __launch_bounds__(512, 4) void sdpa_apply9(const float* __restrict__ Q,
                                                      const uchar* __restrict__ Kimg,
                                                      const uchar* __restrict__ VTimg,
                                                      float* __restrict__ Out) {
  __shared__ __attribute__((aligned(16))) float Comb[8][16 * 68];  // 34816 B

  const int tid = threadIdx.x, lane = tid & 63, w = tid >> 6;
  const int l15 = lane & 15, g4 = lane >> 4;
  const int xcd = blockIdx.x & 7;
  const int b = xcd >> 1;
  const int qt = ((blockIdx.x >> 3) << 1) | (xcd & 1);  // [0,128)

  // Q B-frags: the block's 32 q rows (2 x 16), scaled + hi/lo split
  short8 qh[2][2], ql[2][2];
#pragma unroll
  for (int qg = 0; qg < 2; ++qg) {
    const int qRow = qt * 32 + qg * 16 + l15;
    const float* Qp = Q + ((size_t)(b * S_N + qRow)) * D_N;
    f32x4 x0 = *(const f32x4*)(Qp + g4 * 8);
    f32x4 x1 = *(const f32x4*)(Qp + g4 * 8 + 4);
    f32x4 y0 = *(const f32x4*)(Qp + 32 + g4 * 8);
    f32x4 y1 = *(const f32x4*)(Qp + 36 + g4 * 8);
    x0 *= QSC; x1 *= QSC; y0 *= QSC; y1 *= QSC;
    splitFrag8(x0, x1, qh[qg][0], ql[qg][0]);
    splitFrag8(y0, y1, qh[qg][1], ql[qg][1]);
  }

  f32x4 accO[2][4];
#pragma unroll
  for (int qg = 0; qg < 2; ++qg)
#pragma unroll
    for (int dt = 0; dt < 4; ++dt) accO[qg][dt] = (f32x4){0.f, 0.f, 0.f, 0.f};

  const uchar* Kc = Kimg + ((size_t)(b * NCHUNK + w * 16)) * IMG_CH + lane * 16;
  const uchar* Vc = VTimg + ((size_t)(b * NCHUNK + w * 16)) * IMG_CH + lane * 16;

#pragma unroll 1
  for (int it = 0; it < 16; ++it) {
    // K(it): loop-local single buffer (dead after QK)
    short8 kb[2][4];
    {
      const uchar* Kn = Kc + (size_t)it * IMG_CH;
#pragma unroll
      for (int kt = 0; kt < 2; ++kt)
#pragma unroll
        for (int p = 0; p < 4; ++p)
          kb[kt][p] = *(const short8*)(Kn + (kt * 4 + p) * 1024);
    }

    // QK(it), swapped (A=K, B=Q): D[k][q]; lane holds k = kt*16+g4*4+r, q=l15.
    // exp results pack directly into the PV A-fragment (permuted-VT trick).
    u32x4 paH[2], paL[2];
#pragma unroll
    for (int kt = 0; kt < 2; ++kt) {
      short8 ah0 = kb[kt][0], ah1 = kb[kt][1];
      short8 al0 = kb[kt][2], al1 = kb[kt][3];
#pragma unroll
      for (int qg = 0; qg < 2; ++qg) {
        f32x4 acc = {0.f, 0.f, 0.f, 0.f};
        acc = MFMA16(al0, qh[qg][0], acc);
        acc = MFMA16(ah0, ql[qg][0], acc);
        acc = MFMA16(ah0, qh[qg][0], acc);
        acc = MFMA16(al1, qh[qg][1], acc);
        acc = MFMA16(ah1, ql[qg][1], acc);
        acc = MFMA16(ah1, qh[qg][1], acc);
#pragma unroll
        for (int pair = 0; pair < 2; ++pair) {
          float p0 = exp2f(fminf(acc[2 * pair + 0], 86.f));
          float p1 = exp2f(fminf(acc[2 * pair + 1], 86.f));
          unsigned short h0, l0, h1, l1;
          split1(p0, h0, l0);
          split1(p1, h1, l1);
          paH[qg][kt * 2 + pair] = (unsigned)h0 | ((unsigned)h1 << 16);
          paL[qg][kt * 2 + pair] = (unsigned)l0 | ((unsigned)l1 << 16);
        }
      }
    }

    // PV(it): A = in-register P frags, B = permuted-VT frags loaded per-dt
    short8 pah[2], pal[2];
#pragma unroll
    for (int qg = 0; qg < 2; ++qg) {
      pah[qg] = __builtin_bit_cast(short8, paH[qg]);
      pal[qg] = __builtin_bit_cast(short8, paL[qg]);
    }
    {
      const uchar* Vn = Vc + (size_t)it * IMG_CH;
#pragma unroll
      for (int dt = 0; dt < 4; ++dt) {
        short8 vh = *(const short8*)(Vn + dt * 2048);
        short8 vl = *(const short8*)(Vn + dt * 2048 + 1024);
#pragma unroll
        for (int qg = 0; qg < 2; ++qg) {
          accO[qg][dt] = MFMA16(pal[qg], vh, accO[qg][dt]);
          accO[qg][dt] = MFMA16(pah[qg], vl, accO[qg][dt]);
          accO[qg][dt] = MFMA16(pah[qg], vh, accO[qg][dt]);
        }
      }
    }
  }

  // merge 8 k-eighth partials, two 16-q phases (LDS = 34.8KB)
#pragma unroll
  for (int qg = 0; qg < 2; ++qg) {
    {
      float* CombW = Comb[w];
#pragma unroll
      for (int dt = 0; dt < 4; ++dt)
#pragma unroll
        for (int r = 0; r < 4; ++r)
          CombW[((g4 << 2) + r) * 68 + dt * 16 + l15] = accO[qg][dt][r];
    }
    __syncthreads();
    {
      const int row = tid >> 5;        // 0..15
      const int c2 = (tid & 31) * 2;   // 0..62
      f32x2 s = {0.f, 0.f};
#pragma unroll
      for (int w2 = 0; w2 < 8; ++w2)
        s += *(const f32x2*)(&Comb[w2][row * 68 + c2]);
      *(f32x2*)(Out + ((size_t)(b * S_N + qt * 32 + qg * 16 + row)) * D_N + c2) = s;
    }
    __syncthreads();
  }
}

extern "C" void kernel_launch(void* const* d_in, const int* in_sizes, int n_in,
                              void* d_out, int out_size, void* d_ws, size_t ws_size,
                              hipStream_t stream) {
  (void)in_sizes; (void)n_in; (void)out_size;
  const float* Q = (const float*)d_in[0];
  const float* K = (const float*)d_in[1];
  const float* V = (const float*)d_in[2];
  float* out = (float*)d_out;
  uchar* ws = (uchar*)d_ws;

  const size_t imgSz = (size_t)B_N * NCHUNK * IMG_CH;          // 4 MB
  const size_t offK = 0;
  const size_t offQV = imgSz;                                  // Q image; VT aliases after stats
  const size_t offLP = 2 * imgSz;
  const size_t offRC = offLP + (size_t)16 * BS_N * 4;          // lPart 1MB
  const size_t need = offRC + (size_t)BS_N * 4;                // ~9.1 MB (ws >= 10.66MB proven)

  if (ws_size < need) return;
  float* lPart = (float*)(ws + offLP);
  float* rcpl = (float*)(ws + offRC);

  sdpa_prepKQ<<<dim3(1024), dim3(256), 0, stream>>>(K, Q, ws + offK, ws + offQV);
  sdpa_stats8<<<dim3(1024), dim3(256), 0, stream>>>(ws + offK, ws + offQV, lPart);
  sdpa_finalize16<<<dim3(BS_N / 256), dim3(256), 0, stream>>>(lPart, rcpl);
  sdpa_prepV6<<<dim3(512), dim3(256), 0, stream>>>(V, rcpl, ws + offQV);
  sdpa_apply9<<<dim3(512), dim3(512), 0, stream>>>(Q, ws + offK, ws + offQV, out);
}

// Round 9
// 106.680 us; speedup vs baseline: 1.3076x; 1.0078x over previous
//
#include <hip/hip_runtime.h>

// B=4, S=4096, D=64, fp32. Softmax over QUERY axis (per key-column norm):
//   out[b,q,:] = sum_k exp(s[q,k]) * (1/sum_q' exp(s[q',k])) * V[k,:],  s = Q.K^T/8
// v10 = v9 + V staged through wave-private LDS via global_load_lds (zero VGPR,
// vmcnt-tracked, compiler can't sink it): fixes v9's 4 serial per-dt V round
// trips (70us, MfmaUtil 32%, 15TB/s attained < 23TB/s L2 => stall-bound).
// Iter: K reg loads (issued first) | 8x gld_lds V->LDS | QK+exp (covers V) |
// pinned vmcnt(0) | PV from LDS ds_read_b128. No barriers in loop (wave-
// private). LDS 64KB (V) aliased by merge Comb after final barrier.
// Numerics identical (hi/lo split, 3-MFMA products).

#define B_N 4
#define S_N 4096
#define D_N 64
#define BS_N (B_N * S_N)
#define NCHUNK 128            // 32-row chunks per batch
#define IMG_CH 8192           // bytes per chunk in every image
#define QSC (0.125f * 1.44269504088896f)

typedef __attribute__((ext_vector_type(4))) float f32x4;
typedef __attribute__((ext_vector_type(2))) float f32x2;
typedef __attribute__((ext_vector_type(8))) short short8;
typedef __attribute__((ext_vector_type(4))) unsigned u32x4;
typedef unsigned char uchar;

#define MFMA16(A, Bf, C) __builtin_amdgcn_mfma_f32_16x16x32_bf16((A), (Bf), (C), 0, 0, 0)

// Truncation hi/lo split: x == hi + lo + O(2^-16 x); residual exact in fp32.
__device__ __forceinline__ void split1(float x, unsigned short& h, unsigned short& l) {
  union { float f; unsigned u; } t; t.f = x;
  h = (unsigned short)(t.u >> 16);
  union { unsigned u; float f; } hv; hv.u = ((unsigned)h) << 16;
  union { float f; unsigned u; } r; r.f = x - hv.f;
  l = (unsigned short)(r.u >> 16);
}

__device__ __forceinline__ void splitFrag8(const f32x4 a, const f32x4 b, short8& hi, short8& lo) {
#pragma unroll
  for (int j = 0; j < 4; ++j) { unsigned short h, l; split1(a[j], h, l); hi[j] = (short)h; lo[j] = (short)l; }
#pragma unroll
  for (int j = 0; j < 4; ++j) { unsigned short h, l; split1(b[j], h, l); hi[4 + j] = (short)h; lo[4 + j] = (short)l; }
}

__device__ __forceinline__ void gld16(const void* g, void* l) {
  __builtin_amdgcn_global_load_lds((const __attribute__((address_space(1))) unsigned int*)g,
                                   (__attribute__((address_space(3))) unsigned int*)l, 16, 0, 0);
}

// ---------------------------------------------------------------------------
// prepKQ: fp32 [B*S][64] -> FRAGMENT-ORDERED chunk images.
// Chunk (8KB) = 2 half-chunks (kt16) x 4 segs (hi-d0..31, hi-d32..63,
// lo-d0..31, lo-d32..63) x 1KB; addr = kt16*4096 + p*1024 + lane*16.
// grid 1024: blocks 0..511 = K (scale 1), 512..1023 = Q (scale QSC).
// ---------------------------------------------------------------------------
__global__ __launch_bounds__(256) void sdpa_prepKQ(const float* __restrict__ K,
                                                   const float* __restrict__ Qm,
                                                   uchar* __restrict__ Kimg,
                                                   uchar* __restrict__ Qimg) {
  const int sel = blockIdx.x >> 9;
  const int c = blockIdx.x & 127;
  const int b = (blockIdx.x >> 7) & 3;
  const float* src = sel ? Qm : K;
  uchar* img = sel ? Qimg : Kimg;
  const float scale = sel ? QSC : 1.0f;
  const int t = threadIdx.x;
  const int r = t >> 3;          // 0..31 row in chunk
  const int d0 = (t & 7) * 8;    // 0..56
  const float* s = src + ((size_t)(b * S_N + c * 32 + r)) * D_N + d0;
  f32x4 x0 = *(const f32x4*)(s);
  f32x4 x1 = *(const f32x4*)(s + 4);
  x0 *= scale; x1 *= scale;
  short8 h8, l8;
  splitFrag8(x0, x1, h8, l8);
  const int kt = r >> 4;
  const int lane = ((d0 & 31) >> 3) * 16 + (r & 15);
  const int ph = d0 >> 5;  // 0/1
  uchar* base = img + ((size_t)(b * NCHUNK + c)) * IMG_CH + kt * 4096 + lane * 16;
  *(short8*)(base + ph * 1024) = h8;
  *(short8*)(base + (2 + ph) * 1024) = l8;
}

// ---------------------------------------------------------------------------
// stats8: lPart[qs][b][k] = sum over q-slice qs (16 slices x 256 q) of
// exp2(min(s,86)). grid 1024 (16 waves/CU), block 256; wave w -> qs = qsg*4+w.
// 64 k register-resident per wave (kh/kl[4][2]); streams 8 Q chunks.
// ---------------------------------------------------------------------------
__global__ __launch_bounds__(256, 4) void sdpa_stats8(const uchar* __restrict__ Kimg,
                                                      const uchar* __restrict__ Qimg,
                                                      float* __restrict__ lPart) {
  const int tid = threadIdx.x, lane = tid & 63, w = tid >> 6;
  const int l15 = lane & 15, g4 = lane >> 4;
  const int xcd = blockIdx.x & 7;
  const int b = xcd >> 1;
  const int r = blockIdx.x >> 3;                  // [0,128)
  const int kt = ((r & 31) << 1) | (xcd & 1);     // [0,64) 64-k tile
  const int qs = ((r >> 5) << 2) | w;             // [0,16) 256-q slice

  // K resident: kg 0..3 -> rows kt*64 + kg*16 + l15; chunk kt*2+(kg>>1), half kg&1
  short8 kh[4][2], kl[4][2];
#pragma unroll
  for (int kg = 0; kg < 4; ++kg) {
    const uchar* kc = Kimg + ((size_t)(b * NCHUNK + kt * 2 + (kg >> 1))) * IMG_CH
                    + (kg & 1) * 4096 + lane * 16;
    kh[kg][0] = *(const short8*)(kc);
    kh[kg][1] = *(const short8*)(kc + 1024);
    kl[kg][0] = *(const short8*)(kc + 2048);
    kl[kg][1] = *(const short8*)(kc + 3072);
  }

  float lacc[4][4];
#pragma unroll
  for (int kg = 0; kg < 4; ++kg)
#pragma unroll
    for (int rr = 0; rr < 4; ++rr) lacc[kg][rr] = 0.f;

  const uchar* Qbase = Qimg + ((size_t)(b * NCHUNK + qs * 8)) * IMG_CH + lane * 16;

#pragma unroll 1
  for (int it = 0; it < 8; ++it) {
    const uchar* Qc = Qbase + (size_t)it * IMG_CH;
#pragma unroll
    for (int qt = 0; qt < 2; ++qt) {
      short8 bh0 = *(const short8*)(Qc + qt * 4096);
      short8 bh1 = *(const short8*)(Qc + qt * 4096 + 1024);
      short8 bl0 = *(const short8*)(Qc + qt * 4096 + 2048);
      short8 bl1 = *(const short8*)(Qc + qt * 4096 + 3072);
#pragma unroll
      for (int kg = 0; kg < 4; ++kg) {
        f32x4 acc = {0.f, 0.f, 0.f, 0.f};
        acc = MFMA16(kl[kg][0], bh0, acc);
        acc = MFMA16(kh[kg][0], bl0, acc);
        acc = MFMA16(kh[kg][0], bh0, acc);
        acc = MFMA16(kl[kg][1], bh1, acc);
        acc = MFMA16(kh[kg][1], bl1, acc);
        acc = MFMA16(kh[kg][1], bh1, acc);
#pragma unroll
        for (int rr = 0; rr < 4; ++rr)
          lacc[kg][rr] += exp2f(fminf(acc[rr], 86.f));
      }
    }
  }

#pragma unroll
  for (int off = 1; off < 16; off <<= 1)
#pragma unroll
    for (int kg = 0; kg < 4; ++kg)
#pragma unroll
      for (int rr = 0; rr < 4; ++rr)
        lacc[kg][rr] += __shfl_xor(lacc[kg][rr], off);

  if (l15 == 0) {
#pragma unroll
    for (int kg = 0; kg < 4; ++kg)
#pragma unroll
      for (int rr = 0; rr < 4; ++rr)
        lPart[(size_t)qs * BS_N + b * S_N + kt * 64 + kg * 16 + (g4 << 2) + rr] = lacc[kg][rr];
  }
}

__global__ void sdpa_finalize16(const float* __restrict__ lPart, float* __restrict__ rcpl) {
  int i = blockIdx.x * 256 + threadIdx.x;
  if (i < BS_N) {
    float s = 0.f;
#pragma unroll
    for (int j = 0; j < 16; ++j) s += lPart[(size_t)j * BS_N + i];
    rcpl[i] = 1.0f / s;
  }
}

// ---------------------------------------------------------------------------
// prepV6: fragment-ordered VT chunk images with PERMUTED k-columns.
// Chunk = 4 dt x [hi 1KB | lo 1KB]; addr = dt*2048 + half*1024 + lane*16;
// d = dt*16 + (lane&15), col slots cc = (lane>>4)*8..+7,
// value = split(V[k=perm(cc)][d]*rcpl[k]), perm(c)=((c>>2)&1)*16+((c>>3)<<2)+(c&3).
// ---------------------------------------------------------------------------
__global__ __launch_bounds__(256) void sdpa_prepV6(const float* __restrict__ V,
                                                   const float* __restrict__ rcpl,
                                                   uchar* __restrict__ VT) {
  __shared__ float Vs[32][65];
  __shared__ float rls[32];
  const int c = blockIdx.x & 127;
  const int b = blockIdx.x >> 7;
  const int t = threadIdx.x;
  {
    const int k = t >> 3;
    const int d0 = (t & 7) * 8;
    const float* src = V + ((size_t)(b * S_N + c * 32 + k)) * D_N + d0;
    f32x4 x0 = *(const f32x4*)(src);
    f32x4 x1 = *(const f32x4*)(src + 4);
#pragma unroll
    for (int j = 0; j < 4; ++j) { Vs[k][d0 + j] = x0[j]; Vs[k][d0 + 4 + j] = x1[j]; }
    if (t < 32) rls[t] = rcpl[b * S_N + c * 32 + t];
  }
  __syncthreads();
  const int d = t >> 2;
  const int kg = t & 3;
  short8 h8, l8;
#pragma unroll
  for (int j = 0; j < 8; ++j) {
    const int cc = kg * 8 + j;
    const int k = (((cc >> 2) & 1) << 4) + (((cc >> 3)) << 2) + (cc & 3);
    float v = Vs[k][d] * rls[k];
    unsigned short h, l; split1(v, h, l);
    h8[j] = (short)h; l8[j] = (short)l;
  }
  const int lane = kg * 16 + (d & 15);
  uchar* base = VT + ((size_t)(b * NCHUNK + c)) * IMG_CH + (d >> 4) * 2048 + lane * 16;
  *(short8*)(base) = h8;
  *(short8*)(base + 1024) = l8;
}

// ---------------------------------------------------------------------------
// apply10: grid 512 = b(4, XCD-paired) x qt(128 tiles of 32 q); block 512 =
// 8 waves, wave w = k-EIGHTH (16 chunks); waves share the 32-q tile (2 qg).
// 16 waves/CU. Per iter: K reg loads (first) | V chunk -> wave-private LDS via
// global_load_lds (8 ops, no VGPR) | QK+exp covers V latency | pinned
// vmcnt(0) | PV from LDS. LDS: 8 waves x 8KB = 64KB, merge Comb aliases it.
// ---------------------------------------------------------------------------
__global__ __launch_bounds__(512, 4) void sdpa_apply10(const float* __restrict__ Q,
                                                       const uchar* __restrict__ Kimg,
                                                       const uchar* __restrict__ VTimg,
                                                       float* __restrict__ Out) {
  __shared__ __attribute__((aligned(16))) uchar sm[65536];  // V slabs; Comb aliases

  const int tid = threadIdx.x, lane = tid & 63, w = tid >> 6;
  const int l15 = lane & 15, g4 = lane >> 4;
  const int xcd = blockIdx.x & 7;
  const int b = xcd >> 1;
  const int qt = ((blockIdx.x >> 3) << 1) | (xcd & 1);  // [0,128)

  // Q B-frags: the block's 32 q rows (2 x 16), scaled + hi/lo split
  short8 qh[2][2], ql[2][2];
#pragma unroll
  for (int qg = 0; qg < 2; ++qg) {
    const int qRow = qt * 32 + qg * 16 + l15;
    const float* Qp = Q + ((size_t)(b * S_N + qRow)) * D_N;
    f32x4 x0 = *(const f32x4*)(Qp + g4 * 8);
    f32x4 x1 = *(const f32x4*)(Qp + g4 * 8 + 4);
    f32x4 y0 = *(const f32x4*)(Qp + 32 + g4 * 8);
    f32x4 y1 = *(const f32x4*)(Qp + 36 + g4 * 8);
    x0 *= QSC; x1 *= QSC; y0 *= QSC; y1 *= QSC;
    splitFrag8(x0, x1, qh[qg][0], ql[qg][0]);
    splitFrag8(y0, y1, qh[qg][1], ql[qg][1]);
  }

  f32x4 accO[2][4];
#pragma unroll
  for (int qg = 0; qg < 2; ++qg)
#pragma unroll
    for (int dt = 0; dt < 4; ++dt) accO[qg][dt] = (f32x4){0.f, 0.f, 0.f, 0.f};

  const uchar* Kc = Kimg + ((size_t)(b * NCHUNK + w * 16)) * IMG_CH + lane * 16;
  const uchar* Vc = VTimg + ((size_t)(b * NCHUNK + w * 16)) * IMG_CH + lane * 16;
  uchar* ldsV = sm + w * 8192;            // wave-uniform slab base
  const int l16 = lane * 16;

#pragma unroll 1
  for (int it = 0; it < 16; ++it) {
    // K(it): register loads, issued FIRST (QK's vmcnt wait then leaves the
    // later-issued V stage ops in flight).
    short8 kb[2][4];
    {
      const uchar* Kn = Kc + (size_t)it * IMG_CH;
#pragma unroll
      for (int kt = 0; kt < 2; ++kt)
#pragma unroll
        for (int p = 0; p < 4; ++p)
          kb[kt][p] = *(const short8*)(Kn + (kt * 4 + p) * 1024);
    }
    // V(it) -> wave-private LDS (no VGPR, vmcnt-tracked; covered by QK+exp)
    {
      const uchar* Vn = Vc + (size_t)it * IMG_CH;  // per-lane (+lane*16)
#pragma unroll
      for (int s = 0; s < 8; ++s)
        gld16(Vn + s * 1024, ldsV + s * 1024);
    }

    // QK(it), swapped (A=K, B=Q): D[k][q]; lane holds k = kt*16+g4*4+r, q=l15.
    // exp results pack directly into the PV A-fragment (permuted-VT trick).
    u32x4 paH[2], paL[2];
#pragma unroll
    for (int kt = 0; kt < 2; ++kt) {
      short8 ah0 = kb[kt][0], ah1 = kb[kt][1];
      short8 al0 = kb[kt][2], al1 = kb[kt][3];
#pragma unroll
      for (int qg = 0; qg < 2; ++qg) {
        f32x4 acc = {0.f, 0.f, 0.f, 0.f};
        acc = MFMA16(al0, qh[qg][0], acc);
        acc = MFMA16(ah0, ql[qg][0], acc);
        acc = MFMA16(ah0, qh[qg][0], acc);
        acc = MFMA16(al1, qh[qg][1], acc);
        acc = MFMA16(ah1, ql[qg][1], acc);
        acc = MFMA16(ah1, qh[qg][1], acc);
#pragma unroll
        for (int pair = 0; pair < 2; ++pair) {
          float p0 = exp2f(fminf(acc[2 * pair + 0], 86.f));
          float p1 = exp2f(fminf(acc[2 * pair + 1], 86.f));
          unsigned short h0, l0, h1, l1;
          split1(p0, h0, l0);
          split1(p1, h1, l1);
          paH[qg][kt * 2 + pair] = (unsigned)h0 | ((unsigned)h1 << 16);
          paL[qg][kt * 2 + pair] = (unsigned)l0 | ((unsigned)l1 << 16);
        }
      }
    }

    short8 pah[2], pal[2];
#pragma unroll
    for (int qg = 0; qg < 2; ++qg) {
      pah[qg] = __builtin_bit_cast(short8, paH[qg]);
      pal[qg] = __builtin_bit_cast(short8, paL[qg]);
    }

    // V staged; pin: stage ops stay above, ds_reads stay below.
    asm volatile("s_waitcnt vmcnt(0)" ::: "memory");

    // PV(it): A = in-register P frags, B = V frags from wave-private LDS
#pragma unroll
    for (int dt = 0; dt < 4; ++dt) {
      short8 vh = *(const short8*)(ldsV + dt * 2048 + l16);
      short8 vl = *(const short8*)(ldsV + dt * 2048 + 1024 + l16);
#pragma unroll
      for (int qg = 0; qg < 2; ++qg) {
        accO[qg][dt] = MFMA16(pal[qg], vh, accO[qg][dt]);
        accO[qg][dt] = MFMA16(pah[qg], vl, accO[qg][dt]);
        accO[qg][dt] = MFMA16(pah[qg], vh, accO[qg][dt]);
      }
    }
  }

  // merge 8 k-eighth partials, two 16-q phases (Comb aliases the V slabs)
  float* Comb = (float*)sm;
#pragma unroll
  for (int qg = 0; qg < 2; ++qg) {
    __syncthreads();   // all waves' V reads done / previous phase consumed
    {
      float* CombW = Comb + w * (16 * 68);
#pragma unroll
      for (int dt = 0; dt < 4; ++dt)
#pragma unroll
        for (int r = 0; r < 4; ++r)
          CombW[((g4 << 2) + r) * 68 + dt * 16 + l15] = accO[qg][dt][r];
    }
    __syncthreads();
    {
      const int row = tid >> 5;        // 0..15
      const int c2 = (tid & 31) * 2;   // 0..62
      f32x2 s = {0.f, 0.f};
#pragma unroll
      for (int w2 = 0; w2 < 8; ++w2)
        s += *(const f32x2*)(Comb + w2 * (16 * 68) + row * 68 + c2);
      *(f32x2*)(Out + ((size_t)(b * S_N + qt * 32 + qg * 16 + row)) * D_N + c2) = s;
    }
  }
}

extern "C" void kernel_launch(void* const* d_in, const int* in_sizes, int n_in,
                              void* d_out, int out_size, void* d_ws, size_t ws_size,
                              hipStream_t stream) {
  (void)in_sizes; (void)n_in; (void)out_size;
  const float* Q = (const float*)d_in[0];
  const float* K = (const float*)d_in[1];
  const float* V = (const float*)d_in[2];
  float* out = (float*)d_out;
  uchar* ws = (uchar*)d_ws;

  const size_t imgSz = (size_t)B_N * NCHUNK * IMG_CH;          // 4 MB
  const size_t offK = 0;
  const size_t offQV = imgSz;                                  // Q image; VT aliases after stats
  const size_t offLP = 2 * imgSz;
  const size_t offRC = offLP + (size_t)16 * BS_N * 4;          // lPart 1MB
  const size_t need = offRC + (size_t)BS_N * 4;                // ~9.1 MB (ws >= proven)

  if (ws_size < need) return;
  float* lPart = (float*)(ws + offLP);
  float* rcpl = (float*)(ws + offRC);

  sdpa_prepKQ<<<dim3(1024), dim3(256), 0, stream>>>(K, Q, ws + offK, ws + offQV);
  sdpa_stats8<<<dim3(1024), dim3(256), 0, stream>>>(ws + offK, ws + offQV, lPart);
  sdpa_finalize16<<<dim3(BS_N / 256), dim3(256), 0, stream>>>(lPart, rcpl);
  sdpa_prepV6<<<dim3(512), dim3(256), 0, stream>>>(V, rcpl, ws + offQV);
  sdpa_apply10<<<dim3(512), dim3(512), 0, stream>>>(Q, ws + offK, ws + offQV, out);
}